// Round 2
// baseline (482.799 us; speedup 1.0000x reference)
//
#include <hip/hip_runtime.h>
#include <hip/hip_bf16.h>

#define KT    16
#define NPER  16384
#define DIN   256
#define DOUT  256
#define NTOT  (KT * NPER)

typedef __attribute__((ext_vector_type(8))) short  short8;
typedef __attribute__((ext_vector_type(4))) float  f32x4;
typedef __attribute__((ext_vector_type(4))) unsigned int uint32x4;

// fp32 -> bf16 round-to-nearest-even (bit twiddle; no NaN in this data)
__device__ __forceinline__ unsigned int f2bf(float f) {
    unsigned int u = __float_as_uint(f);
    u += 0x7fffu + ((u >> 16) & 1u);
    return u >> 16;
}

// tanh(y) = sign(y) * (1 - t) / (1 + t),  t = exp(-2|y|)  (stable, no overflow)
__device__ __forceinline__ float fast_tanh(float y) {
    float a = fabsf(y);
    float t = __expf(-2.0f * a);
    float r = (1.0f - t) * __builtin_amdgcn_rcpf(1.0f + t);
    return copysignf(r, y);
}

// ---- prep kernels -----------------------------------------------------------

__global__ void prep_w(const float* __restrict__ w, unsigned short* __restrict__ wbf) {
    int i = blockIdx.x * blockDim.x + threadIdx.x;    // 262144 float4 groups
    float4 v = ((const float4*)w)[i];
    unsigned int p0 = f2bf(v.x) | (f2bf(v.y) << 16);
    unsigned int p1 = f2bf(v.z) | (f2bf(v.w) << 16);
    ((uint2*)wbf)[i] = make_uint2(p0, p1);
}

__global__ void prep_inv(const int* __restrict__ perm, int* __restrict__ inv) {
    int i = blockIdx.x * blockDim.x + threadIdx.x;    // NTOT threads
    inv[perm[i]] = i;
}

// ---- main GEMM + scatter + tanh --------------------------------------------
// Block tile: BM=128 x BN=256 (full D_OUT -> x read exactly once), BK=32,
// 8 K-stages, double-buffered LDS, register prefetch of stage s+1 issued
// right after the barrier so HBM latency overlaps stage-s MFMA.
// 512 threads = 8 waves, each wave 64x64 via 4x4 grid of 16x16x32 mfma.
// LDS rows padded to 40 bf16 (80 B stride): b128 fragment reads tile all 32
// banks across 8 consecutive rows -> conflict-free (2-way max, free).

#define PADK 40

__launch_bounds__(512, 4)
__global__ void gemm_scatter(const float* __restrict__ x,
                             const unsigned short* __restrict__ wbf,
                             const int* __restrict__ inv,
                             float* __restrict__ out) {
    __shared__ unsigned short aLds[2 * 128 * PADK];   // 20 KiB
    __shared__ unsigned short bLds[2 * 256 * PADK];   // 40 KiB
    __shared__ int invLds[128];

    const int tid = threadIdx.x;
    const int bid = blockIdx.x;
    const int kt  = bid >> 7;          // 16 types
    const int rt  = bid & 127;         // 128 row tiles per type

    const float*          xblk = x   + (size_t)(kt * NPER + rt * 128) * DIN;
    const unsigned short* wblk = wbf + (size_t)kt * DOUT * DIN;

    if (tid < 128) invLds[tid] = inv[kt * NPER + rt * 128 + tid];

    const int lane = tid & 63;
    const int wv   = tid >> 6;     // 0..7
    const int wm   = wv & 1;       // row half (0..1)
    const int wn   = wv >> 1;      // col quarter (0..3)
    const int lo   = lane & 15;
    const int hi   = lane >> 4;

    // staging indices: A = 128 rows x 32 cols fp32, float4/thread, 2 iters
    //                  B = 256 rows x 32 cols bf16, 8 bf16/thread, 2 iters
    f32x4 acc[4][4];
#pragma unroll
    for (int i = 0; i < 4; i++)
#pragma unroll
        for (int j = 0; j < 4; j++) acc[i][j] = (f32x4){0.f, 0.f, 0.f, 0.f};

    float4   pa[2];
    uint32x4 pb[2];

    // prologue: load + stage s=0 into buffer 0
#pragma unroll
    for (int it = 0; it < 2; it++) {
        int idx = tid + it * 512, row = idx >> 3, c4 = idx & 7;
        pa[it] = *(const float4*)(xblk + row * DIN + c4 * 4);
    }
#pragma unroll
    for (int it = 0; it < 2; it++) {
        int idx = tid + it * 512, row = idx >> 2, c8 = idx & 3;
        pb[it] = *(const uint32x4*)(wblk + row * DIN + c8 * 8);
    }
#pragma unroll
    for (int it = 0; it < 2; it++) {
        int idx = tid + it * 512, row = idx >> 3, c4 = idx & 7;
        uint2 pk;
        pk.x = f2bf(pa[it].x) | (f2bf(pa[it].y) << 16);
        pk.y = f2bf(pa[it].z) | (f2bf(pa[it].w) << 16);
        *(uint2*)&aLds[row * PADK + c4 * 4] = pk;
    }
#pragma unroll
    for (int it = 0; it < 2; it++) {
        int idx = tid + it * 512, row = idx >> 2, c8 = idx & 3;
        *(uint32x4*)&bLds[row * PADK + c8 * 8] = pb[it];
    }

    for (int s = 0; s < 8; ++s) {
        __syncthreads();   // buf[s&1] staged for everyone; buf[(s+1)&1] reads done

        if (s < 7) {       // issue next-stage loads; they fly during compute
            const int d1 = (s + 1) * 32;
#pragma unroll
            for (int it = 0; it < 2; it++) {
                int idx = tid + it * 512, row = idx >> 3, c4 = idx & 7;
                pa[it] = *(const float4*)(xblk + row * DIN + d1 + c4 * 4);
            }
#pragma unroll
            for (int it = 0; it < 2; it++) {
                int idx = tid + it * 512, row = idx >> 2, c8 = idx & 3;
                pb[it] = *(const uint32x4*)(wblk + row * DIN + d1 + c8 * 8);
            }
        }

        const unsigned short* aB = &aLds[(s & 1) * 128 * PADK];
        const unsigned short* bB = &bLds[(s & 1) * 256 * PADK];
        short8 af[4], bfr[4];
#pragma unroll
        for (int i = 0; i < 4; i++)
            af[i] = *(const short8*)&aB[(wm * 64 + i * 16 + lo) * PADK + hi * 8];
#pragma unroll
        for (int j = 0; j < 4; j++)
            bfr[j] = *(const short8*)&bB[(wn * 64 + j * 16 + lo) * PADK + hi * 8];
#pragma unroll
        for (int i = 0; i < 4; i++)
#pragma unroll
            for (int j = 0; j < 4; j++)
                acc[i][j] = __builtin_amdgcn_mfma_f32_16x16x32_bf16(
                    af[i], bfr[j], acc[i][j], 0, 0, 0);

        if (s < 7) {       // land prefetch into the other buffer
            unsigned short* aW = &aLds[((s + 1) & 1) * 128 * PADK];
            unsigned short* bW = &bLds[((s + 1) & 1) * 256 * PADK];
#pragma unroll
            for (int it = 0; it < 2; it++) {
                int idx = tid + it * 512, row = idx >> 3, c4 = idx & 7;
                uint2 pk;
                pk.x = f2bf(pa[it].x) | (f2bf(pa[it].y) << 16);
                pk.y = f2bf(pa[it].z) | (f2bf(pa[it].w) << 16);
                *(uint2*)&aW[row * PADK + c4 * 4] = pk;
            }
#pragma unroll
            for (int it = 0; it < 2; it++) {
                int idx = tid + it * 512, row = idx >> 2, c8 = idx & 3;
                *(uint32x4*)&bW[row * PADK + c8 * 8] = pb[it];
            }
        }
    }

    // epilogue: tanh + permuted row scatter (nontemporal — output is streamed).
    // C/D layout: col = lane&15, row = (lane>>4)*4 + reg   [measured m89/m91]
#pragma unroll
    for (int i = 0; i < 4; i++) {
#pragma unroll
        for (int r = 0; r < 4; r++) {
            int rowL = wm * 64 + i * 16 + hi * 4 + r;
            size_t orow = (size_t)invLds[rowL];
            float* op = out + orow * DOUT;
#pragma unroll
            for (int j = 0; j < 4; j++) {
                int col = wn * 64 + j * 16 + lo;
                __builtin_nontemporal_store(fast_tanh(acc[i][j][r]), op + col);
            }
        }
    }
}

// ---- launch -----------------------------------------------------------------

extern "C" void kernel_launch(void* const* d_in, const int* in_sizes, int n_in,
                              void* d_out, int out_size, void* d_ws, size_t ws_size,
                              hipStream_t stream) {
    const float* x    = (const float*)d_in[0];   // [16,16384,256] fp32
    const float* w    = (const float*)d_in[1];   // [16,256,256]  fp32
    const int*   perm = (const int*)d_in[2];     // [262144]      int32
    float*       out  = (float*)d_out;           // [262144,256]  fp32

    unsigned short* wbf = (unsigned short*)d_ws;                         // 2 MiB
    int*            inv = (int*)((char*)d_ws + (size_t)2 * 1024 * 1024); // 1 MiB

    prep_w  <<<1024, 256, 0, stream>>>(w, wbf);      // 16*256*256/4 float4s
    prep_inv<<<1024, 256, 0, stream>>>(perm, inv);   // NTOT threads
    gemm_scatter<<<KT * 128, 512, 0, stream>>>(x, wbf, inv, out);
}